// Round 1
// 1173.850 us; speedup vs baseline: 3.6150x; 3.6150x over previous
//
#include <hip/hip_runtime.h>

// MemoryRotaryAttend via MFMA flash attention.
// q/k/v fp32 (4,32,512,128), mem_kv fp32 (2,4,4096,32,128), start_pos scalar (=2048).
// QK^T: bf16x3 split (Khi*Qhi + Khi*Qlo + Klo*Qhi) -> fp32-grade scores.
// PV:   single-bf16 V and P (error ~2e-4), P fragment = QK^T output regs (swapped layouts).
#define BB   4
#define NN   32
#define SS   512
#define DD   128
#define NMEM 4096
#define MAXB 4
#define MQ   64     // q rows per block (16 per wave)
#define NK   64     // keys per LDS tile

typedef __attribute__((ext_vector_type(8))) short short8;
typedef __attribute__((ext_vector_type(4))) short short4v;
typedef __attribute__((ext_vector_type(4))) float f32x4;

__device__ __forceinline__ ushort bf16_rne(float x) {
    unsigned u = __float_as_uint(x);
    return (ushort)((u + 0x7FFFu + ((u >> 16) & 1u)) >> 16);
}

__device__ __forceinline__ void split_bf16(float x, ushort& hi, ushort& lo) {
    ushort hb = bf16_rne(x);
    float hf = __uint_as_float(((unsigned)hb) << 16);
    hi = hb;
    lo = bf16_rne(x - hf);   // x - hf is exact in fp32
}

__device__ __forceinline__ void load_kv_row(const float* __restrict__ kg,
                                            const float* __restrict__ vg,
                                            const float* __restrict__ mg,
                                            int batch, int head, int start_pos, int T,
                                            int t, int d0, float nlb,
                                            float* kb, float* vb)
{
    if (t < start_pos) {
        const float* ks = mg + (((long)batch * NMEM + t) * NN + head) * DD + d0;
        const float* vs = ks + (long)MAXB * NMEM * NN * DD;
        float4 kk = *(const float4*)ks;
        float4 vv = *(const float4*)vs;
        kb[0] = kk.x; kb[1] = kk.y; kb[2] = kk.z; kb[3] = kk.w;
        vb[0] = vv.x; vb[1] = vv.y; vb[2] = vv.z; vb[3] = vv.w;
    } else if (t < T) {
        const long off = (((long)(batch * NN + head)) * SS + (t - start_pos)) * DD + d0;
        float4 kk = *(const float4*)(kg + off);
        float4 vv = *(const float4*)(vg + off);
        float sn, cs;
        sincosf((float)t * __expf(nlb * (float)d0), &sn, &cs);
        kb[0] = kk.x * cs - kk.y * sn;
        kb[1] = kk.x * sn + kk.y * cs;
        sincosf((float)t * __expf(nlb * (float)(d0 + 2)), &sn, &cs);
        kb[2] = kk.z * cs - kk.w * sn;
        kb[3] = kk.z * sn + kk.w * cs;
        vb[0] = vv.x; vb[1] = vv.y; vb[2] = vv.z; vb[3] = vv.w;
    } else {
        kb[0] = kb[1] = kb[2] = kb[3] = 0.f;
        vb[0] = vb[1] = vb[2] = vb[3] = 0.f;
    }
}

__global__ __launch_bounds__(256)
void mra_attn_mfma(const float* __restrict__ qg,
                   const float* __restrict__ kg,
                   const float* __restrict__ vg,
                   const float* __restrict__ mg,
                   const int*  __restrict__ spp,
                   float* __restrict__ outg)
{
    const int start_pos = spp[0];
    const int T = start_pos + SS;
    const int ntiles = (T + NK - 1) / NK;

    const int qblk  = blockIdx.x;
    const int head  = blockIdx.y;
    const int batch = blockIdx.z;
    const int tid   = threadIdx.x;
    const int wv    = tid >> 6;       // wave 0..3: owns q rows [wv*16, wv*16+16)
    const int lane  = tid & 63;
    const int h     = lane >> 4;      // k-slot group 0..3
    const int m     = lane & 15;      // A-row / B-col index

    // K tile (hi/lo split) [NK][DD] bf16, row stride 256B, swizzle ^((row&7)<<3) in ushorts.
    // V^T tile [DD][NK] bf16, row stride 128B, swizzle ^((d&15)<<2) in ushorts.
    __shared__ ushort khi[NK * DD];   // 16 KB (also reused for Q_hi staging, [MQ][DD])
    __shared__ ushort klo[NK * DD];   // 16 KB (also reused for Q_lo staging)
    __shared__ ushort vts[DD * NK];   // 16 KB

    const float nlb   = -9.210340371976184f / 128.0f;  // -ln(10000)/d
    const float scale = 0.08838834764831845f;          // 1/sqrt(128)

    // ---- Stage Q tile (rope + scale + hi/lo split) into khi/klo, unswizzled ----
    const int q0 = qblk * MQ;
#pragma unroll
    for (int p = 0; p < 8; ++p) {
        const int idx = p * 1024 + tid * 4;
        const int row = idx >> 7;       // 0..63
        const int col = idx & 127;      // multiple of 4
        const int pos = start_pos + q0 + row;
        float4 x = *(const float4*)(qg + (((long)(batch * NN + head)) * SS + q0 + row) * DD + col);
        float sn, cs;
        sincosf((float)pos * __expf(nlb * (float)col), &sn, &cs);
        float e0 = (x.x * cs - x.y * sn) * scale;
        float e1 = (x.x * sn + x.y * cs) * scale;
        sincosf((float)pos * __expf(nlb * (float)(col + 2)), &sn, &cs);
        float e2 = (x.z * cs - x.w * sn) * scale;
        float e3 = (x.z * sn + x.w * cs) * scale;
        ushort hh[4], ll[4];
        split_bf16(e0, hh[0], ll[0]);
        split_bf16(e1, hh[1], ll[1]);
        split_bf16(e2, hh[2], ll[2]);
        split_bf16(e3, hh[3], ll[3]);
        *(ushort4*)(&khi[row * DD + col]) = make_ushort4(hh[0], hh[1], hh[2], hh[3]);
        *(ushort4*)(&klo[row * DD + col]) = make_ushort4(ll[0], ll[1], ll[2], ll[3]);
    }
    __syncthreads();

    // ---- Q fragments to registers (kept for whole kernel): B-operand slot (l,j) = Q[m][32*dc+8h+j]
    short8 qfh[4], qfl[4];
    {
        const ushort* qrh = &khi[(wv * 16 + m) * DD];
        const ushort* qrl = &klo[(wv * 16 + m) * DD];
#pragma unroll
        for (int dc = 0; dc < 4; ++dc) {
            qfh[dc] = *(const short8*)(qrh + dc * 32 + h * 8);
            qfl[dc] = *(const short8*)(qrl + dc * 32 + h * 8);
        }
    }
    __syncthreads();

    // ---- accumulators: acc[db] reg r  <->  O[d = 16*db + 4h + r][q = m] ----
    f32x4 acc[8];
    const f32x4 zero4 = {0.f, 0.f, 0.f, 0.f};
#pragma unroll
    for (int i = 0; i < 8; ++i) acc[i] = zero4;
    float m_run = -1e30f, l_run = 0.f;

    for (int kt = 0; kt < ntiles; ++kt) {
        const int tile0 = kt * NK;

        // ---- stage K (hi/lo) and V^T: each thread handles 2 rows x 4 cols per pass ----
#pragma unroll
        for (int p = 0; p < 4; ++p) {
            const int pi = p * 256 + tid;
            const int d0 = (pi & 31) * 4;       // 0..124
            const int t0 = (pi >> 5) * 2;       // 0..62 (even)
            float kA[4], vA[4], kB[4], vB[4];
            load_kv_row(kg, vg, mg, batch, head, start_pos, T, tile0 + t0,     d0, nlb, kA, vA);
            load_kv_row(kg, vg, mg, batch, head, start_pos, T, tile0 + t0 + 1, d0, nlb, kB, vB);
            {
                const int co = d0 ^ ((t0 & 7) << 3);
                ushort hh[4], ll[4];
#pragma unroll
                for (int j = 0; j < 4; ++j) split_bf16(kA[j], hh[j], ll[j]);
                *(ushort4*)(&khi[t0 * DD + co]) = make_ushort4(hh[0], hh[1], hh[2], hh[3]);
                *(ushort4*)(&klo[t0 * DD + co]) = make_ushort4(ll[0], ll[1], ll[2], ll[3]);
            }
            {
                const int t1 = t0 + 1;
                const int co = d0 ^ ((t1 & 7) << 3);
                ushort hh[4], ll[4];
#pragma unroll
                for (int j = 0; j < 4; ++j) split_bf16(kB[j], hh[j], ll[j]);
                *(ushort4*)(&khi[t1 * DD + co]) = make_ushort4(hh[0], hh[1], hh[2], hh[3]);
                *(ushort4*)(&klo[t1 * DD + co]) = make_ushort4(ll[0], ll[1], ll[2], ll[3]);
            }
#pragma unroll
            for (int j = 0; j < 4; ++j) {
                const int d = d0 + j;
                unsigned pk = (unsigned)bf16_rne(vA[j]) | ((unsigned)bf16_rne(vB[j]) << 16);
                *(unsigned*)(&vts[d * NK + (t0 ^ ((d & 15) << 2))]) = pk;
            }
        }
        __syncthreads();

        // ---- QK^T: swapped (A=K, B=Q). C-reg r of chunk c = S[key = 16c+4h+r][q = m] ----
        float sc[16];
#pragma unroll
        for (int c = 0; c < 4; ++c) {
            f32x4 s = zero4;
            const int krow = c * 16 + m;
            const ushort* krh = &khi[krow * DD];
            const ushort* krl = &klo[krow * DD];
            const int sw = (krow & 7) << 3;
#pragma unroll
            for (int dc = 0; dc < 4; ++dc) {
                const int o = (dc * 32 + h * 8) ^ sw;
                short8 kfh = *(const short8*)(krh + o);
                short8 kfl = *(const short8*)(krl + o);
                s = __builtin_amdgcn_mfma_f32_16x16x32_bf16(kfh, qfh[dc], s, 0, 0, 0);
                s = __builtin_amdgcn_mfma_f32_16x16x32_bf16(kfh, qfl[dc], s, 0, 0, 0);
                s = __builtin_amdgcn_mfma_f32_16x16x32_bf16(kfl, qfh[dc], s, 0, 0, 0);
            }
            if (tile0 + NK > T) {   // tail mask (zero-padded keys must become -inf)
#pragma unroll
                for (int r = 0; r < 4; ++r)
                    if (tile0 + c * 16 + h * 4 + r >= T) s[r] = -1e30f;
            }
#pragma unroll
            for (int r = 0; r < 4; ++r) sc[c * 4 + r] = s[r];
        }

        // ---- online softmax: lane holds 16 of the row's 64 scores; full row via xor 16/32 ----
        float mloc = sc[0];
#pragma unroll
        for (int i = 1; i < 16; ++i) mloc = fmaxf(mloc, sc[i]);
        mloc = fmaxf(mloc, __shfl_xor(mloc, 16));
        mloc = fmaxf(mloc, __shfl_xor(mloc, 32));
        const float mnew = fmaxf(m_run, mloc);
        float lloc = 0.f;
#pragma unroll
        for (int i = 0; i < 16; ++i) {
            float pv = __expf(sc[i] - mnew);
            sc[i] = pv;
            lloc += pv;
        }
        lloc += __shfl_xor(lloc, 16);
        lloc += __shfl_xor(lloc, 32);
        const float alpha = __expf(m_run - mnew);
        l_run = l_run * alpha + lloc;
        m_run = mnew;
#pragma unroll
        for (int db = 0; db < 8; ++db) acc[db] = acc[db] * alpha;

        // ---- PV: swapped (A=V^T, B=P). Slot mapping t = 32g + 4h + (j&3) + 16*(j>>2)
        //      => P fragment is exactly sc[8g + j] (in registers), V^T frag = 2x ds_read_b64.
#pragma unroll
        for (int g = 0; g < 2; ++g) {
            short8 pf;
#pragma unroll
            for (int j = 0; j < 8; ++j) pf[j] = (short)bf16_rne(sc[g * 8 + j]);
#pragma unroll
            for (int db = 0; db < 8; ++db) {
                const int drow = db * 16 + m;
                const ushort* vr = &vts[drow * NK];
                const int sw = (drow & 15) << 2;
                short4v a0 = *(const short4v*)(vr + ((g * 32 + h * 4) ^ sw));
                short4v a1 = *(const short4v*)(vr + ((g * 32 + 16 + h * 4) ^ sw));
                short8 vf = __builtin_shufflevector(a0, a1, 0, 1, 2, 3, 4, 5, 6, 7);
                acc[db] = __builtin_amdgcn_mfma_f32_16x16x32_bf16(vf, pf, acc[db], 0, 0, 0);
            }
        }
        __syncthreads();
    }

    // ---- epilogue: lane l, acc[db] reg r -> out[q0 + 16wv + m][16db + 4h + r] ----
    const float inv_l = 1.f / l_run;
    float* dst = outg + (((long)(batch * NN + head)) * SS + q0 + wv * 16 + m) * DD;
#pragma unroll
    for (int db = 0; db < 8; ++db) {
        float4 o = make_float4(acc[db][0] * inv_l, acc[db][1] * inv_l,
                               acc[db][2] * inv_l, acc[db][3] * inv_l);
        *(float4*)(dst + db * 16 + h * 4) = o;
    }
}

extern "C" void kernel_launch(void* const* d_in, const int* in_sizes, int n_in,
                              void* d_out, int out_size, void* d_ws, size_t ws_size,
                              hipStream_t stream) {
    const float* q      = (const float*)d_in[0];
    const float* k      = (const float*)d_in[1];
    const float* v      = (const float*)d_in[2];
    const float* mem_kv = (const float*)d_in[3];
    const int*   sp     = (const int*)d_in[4];
    float* out = (float*)d_out;

    dim3 grid(SS / MQ, NN, BB);   // (8, 32, 4)
    dim3 block(256);
    hipLaunchKernelGGL(mra_attn_mfma, grid, block, 0, stream, q, k, v, mem_kv, sp, out);
}

// Round 2
// 1031.136 us; speedup vs baseline: 4.1154x; 1.1384x over previous
//
#include <hip/hip_runtime.h>

// MemoryRotaryAttend via MFMA flash attention, v2.
// q/k/v fp32 (4,32,512,128), mem_kv fp32 (2,4,4096,32,128), start_pos scalar (=2048).
// QK^T: bf16x3 split (Kh*Qh + Kh*Ql + Kl*Qh), truncate-hi + rne-lo -> fp32-grade scores.
// PV:   single-bf16 V and P; P fragment = QK^T output regs (swapped layouts, no shuffles).
// v2: 512 threads / 8 waves, MQ=128 (halves staging redundancy), Q roped in registers,
//     per-tile uniform mem/new path specialization, hoisted inv_freq, XCD work grouping.
#define BB   4
#define NN   32
#define SS   512
#define DD   128
#define NMEM 4096
#define MAXB 4
#define MQ   128    // q rows per block (16 per wave, 8 waves)
#define NK   64     // keys per LDS tile
#define VOFF ((long)MAXB * NMEM * NN * DD)

typedef __attribute__((ext_vector_type(8))) short short8;
typedef __attribute__((ext_vector_type(4))) short short4v;
typedef __attribute__((ext_vector_type(4))) float f32x4;

__device__ __forceinline__ ushort bf16_rne(float x) {
    unsigned u = __float_as_uint(x);
    return (ushort)((u + 0x7FFFu + ((u >> 16) & 1u)) >> 16);
}

// hi = truncation (error exactly captured by lo), lo = rne(residual): sum error ~2^-17 |x|.
__device__ __forceinline__ void split_bf16(float x, ushort& hi, ushort& lo) {
    unsigned u = __float_as_uint(x);
    hi = (ushort)(u >> 16);
    lo = bf16_rne(x - __uint_as_float(u & 0xffff0000u));
}

// MODE 0: all rows from mem_kv. MODE 1: all rows from new k/v (caller guarantees t<T).
// MODE 2: generic (boundary / tail).
template<int MODE>
__device__ __forceinline__ void fetch_row(const float* __restrict__ kmem,
                                          const float* __restrict__ knew,
                                          const float* __restrict__ vnew,
                                          int t, int start_pos, int T,
                                          float fr0, float fr2,
                                          float* kb, float* vb)
{
    const bool from_mem = (MODE == 0) || (MODE == 2 && t < start_pos);
    if (from_mem) {
        const float* ks = kmem + (long)t * (NN * DD);
        float4 kk = *(const float4*)ks;
        float4 vv = *(const float4*)(ks + VOFF);
        kb[0] = kk.x; kb[1] = kk.y; kb[2] = kk.z; kb[3] = kk.w;
        vb[0] = vv.x; vb[1] = vv.y; vb[2] = vv.z; vb[3] = vv.w;
    } else if (MODE == 1 || t < T) {
        const long off = (long)(t - start_pos) * DD;
        float4 kk = *(const float4*)(knew + off);
        float4 vv = *(const float4*)(vnew + off);
        float sn0, cs0, sn2, cs2;
        sincosf((float)t * fr0, &sn0, &cs0);
        sincosf((float)t * fr2, &sn2, &cs2);
        kb[0] = kk.x * cs0 - kk.y * sn0;
        kb[1] = kk.x * sn0 + kk.y * cs0;
        kb[2] = kk.z * cs2 - kk.w * sn2;
        kb[3] = kk.z * sn2 + kk.w * cs2;
        vb[0] = vv.x; vb[1] = vv.y; vb[2] = vv.z; vb[3] = vv.w;
    } else {
        kb[0] = kb[1] = kb[2] = kb[3] = 0.f;
        vb[0] = vb[1] = vb[2] = vb[3] = 0.f;
    }
}

template<int MODE>
__device__ __forceinline__ void stage_tile(const float* __restrict__ kmem,
                                           const float* __restrict__ knew,
                                           const float* __restrict__ vnew,
                                           int tile0, int start_pos, int T,
                                           int d0, int tr0, float fr0, float fr2,
                                           ushort* __restrict__ khi,
                                           ushort* __restrict__ klo,
                                           ushort* __restrict__ vts)
{
#pragma unroll
    for (int p = 0; p < 2; ++p) {
        const int trr = tr0 + p * 32;               // even, 0..62
        float kA[4], vA[4], kB[4], vB[4];
        fetch_row<MODE>(kmem, knew, vnew, tile0 + trr,     start_pos, T, fr0, fr2, kA, vA);
        fetch_row<MODE>(kmem, knew, vnew, tile0 + trr + 1, start_pos, T, fr0, fr2, kB, vB);
        {
            const int co = d0 ^ ((trr & 7) << 3);
            ushort hh[4], ll[4];
#pragma unroll
            for (int j = 0; j < 4; ++j) split_bf16(kA[j], hh[j], ll[j]);
            *(ushort4*)(&khi[trr * DD + co]) = make_ushort4(hh[0], hh[1], hh[2], hh[3]);
            *(ushort4*)(&klo[trr * DD + co]) = make_ushort4(ll[0], ll[1], ll[2], ll[3]);
        }
        {
            const int t1 = trr + 1;
            const int co = d0 ^ ((t1 & 7) << 3);
            ushort hh[4], ll[4];
#pragma unroll
            for (int j = 0; j < 4; ++j) split_bf16(kB[j], hh[j], ll[j]);
            *(ushort4*)(&khi[t1 * DD + co]) = make_ushort4(hh[0], hh[1], hh[2], hh[3]);
            *(ushort4*)(&klo[t1 * DD + co]) = make_ushort4(ll[0], ll[1], ll[2], ll[3]);
        }
#pragma unroll
        for (int j = 0; j < 4; ++j) {
            const int d = d0 + j;
            unsigned pk = (unsigned)bf16_rne(vA[j]) | ((unsigned)bf16_rne(vB[j]) << 16);
            *(unsigned*)(&vts[d * NK + (trr ^ ((d & 15) << 2))]) = pk;
        }
    }
}

__global__ __launch_bounds__(512, 4)
void mra_attn_mfma(const float* __restrict__ qg,
                   const float* __restrict__ kg,
                   const float* __restrict__ vg,
                   const float* __restrict__ mg,
                   const int*  __restrict__ spp,
                   float* __restrict__ outg)
{
    const int start_pos = spp[0];
    const int T = start_pos + SS;
    const int ntiles = (T + NK - 1) / NK;

    // XCD-grouped work decode: the 4 q-blocks of one (head,batch) land on one XCD's L2.
    const int flat  = blockIdx.x;        // 0..511, dispatch round-robins flat%8 over XCDs
    const int work  = (flat & 7) * 64 + (flat >> 3);
    const int qblk  = work & 3;
    const int grp   = work >> 2;
    const int head  = grp & 31;
    const int batch = grp >> 5;

    const int tid  = threadIdx.x;
    const int wv   = tid >> 6;        // wave 0..7: owns q rows [wv*16, wv*16+16)
    const int lane = tid & 63;
    const int h    = lane >> 4;       // k-slot group 0..3
    const int m    = lane & 15;       // A-row / B-col index

    // K tile (hi/lo split) [NK][DD] bf16, row stride 256B, swizzle ^((row&7)<<3) in ushorts.
    // V^T tile [DD][NK] bf16, row stride 128B, swizzle ^((d&15)<<2) in ushorts.
    __shared__ ushort khi[NK * DD];   // 16 KB
    __shared__ ushort klo[NK * DD];   // 16 KB
    __shared__ ushort vts[DD * NK];   // 16 KB

    const float nlb   = -9.210340371976184f / 128.0f;  // -ln(10000)/d
    const float scale = 0.08838834764831845f;          // 1/sqrt(128)

    // ---- Q tile: load + rope + scale + hi/lo split entirely in registers ----
    const int q0   = qblk * MQ;
    const int qrow = q0 + wv * 16 + m;
    const float pos = (float)(start_pos + qrow);
    const float* qbase = qg + (((long)(batch * NN + head)) * SS + qrow) * DD;
    short8 qfh[4], qfl[4];
#pragma unroll
    for (int dc = 0; dc < 4; ++dc) {
        const int cb = dc * 32 + h * 8;
        float4 xa = *(const float4*)(qbase + cb);
        float4 xb = *(const float4*)(qbase + cb + 4);
        float e[8];
        float f, sn, cs;
        f = __expf(nlb * (float)cb);       sincosf(pos * f, &sn, &cs);
        e[0] = (xa.x * cs - xa.y * sn) * scale;  e[1] = (xa.x * sn + xa.y * cs) * scale;
        f = __expf(nlb * (float)(cb + 2)); sincosf(pos * f, &sn, &cs);
        e[2] = (xa.z * cs - xa.w * sn) * scale;  e[3] = (xa.z * sn + xa.w * cs) * scale;
        f = __expf(nlb * (float)(cb + 4)); sincosf(pos * f, &sn, &cs);
        e[4] = (xb.x * cs - xb.y * sn) * scale;  e[5] = (xb.x * sn + xb.y * cs) * scale;
        f = __expf(nlb * (float)(cb + 6)); sincosf(pos * f, &sn, &cs);
        e[6] = (xb.z * cs - xb.w * sn) * scale;  e[7] = (xb.z * sn + xb.w * cs) * scale;
#pragma unroll
        for (int j = 0; j < 8; ++j) {
            ushort hh, ll;
            split_bf16(e[j], hh, ll);
            qfh[dc][j] = (short)hh;
            qfl[dc][j] = (short)ll;
        }
    }

    // ---- per-thread staging constants (fixed across tiles) ----
    const int d0  = (tid & 31) * 4;          // 0..124
    const int tr0 = (tid >> 5) * 2;          // 0..30 even; pass adds +32
    const float fr0 = __expf(nlb * (float)d0);
    const float fr2 = __expf(nlb * (float)(d0 + 2));
    const float* kmem = mg + (long)batch * NMEM * NN * DD + head * DD + d0;
    const float* knew = kg + (((long)(batch * NN + head)) * SS) * DD + d0;
    const float* vnew = vg + (((long)(batch * NN + head)) * SS) * DD + d0;

    // ---- accumulators: acc[db] reg r  <->  O[d = 16*db + 4h + r][q = m] ----
    f32x4 acc[8];
    const f32x4 zero4 = {0.f, 0.f, 0.f, 0.f};
#pragma unroll
    for (int i = 0; i < 8; ++i) acc[i] = zero4;
    float m_run = -1e30f, l_run = 0.f;

    for (int kt = 0; kt < ntiles; ++kt) {
        const int tile0 = kt * NK;
        __syncthreads();   // prior tile's LDS reads done before overwrite

        if (tile0 + NK <= start_pos)
            stage_tile<0>(kmem, knew, vnew, tile0, start_pos, T, d0, tr0, fr0, fr2, khi, klo, vts);
        else if (tile0 >= start_pos && tile0 + NK <= T)
            stage_tile<1>(kmem, knew, vnew, tile0, start_pos, T, d0, tr0, fr0, fr2, khi, klo, vts);
        else
            stage_tile<2>(kmem, knew, vnew, tile0, start_pos, T, d0, tr0, fr0, fr2, khi, klo, vts);
        __syncthreads();

        // ---- QK^T: swapped (A=K, B=Q). C-reg r of chunk c = S[key = 16c+4h+r][q = m] ----
        float sc[16];
#pragma unroll
        for (int c = 0; c < 4; ++c) {
            f32x4 s = zero4;
            const int krow = c * 16 + m;
            const ushort* krh = &khi[krow * DD];
            const ushort* krl = &klo[krow * DD];
            const int sw = (krow & 7) << 3;
#pragma unroll
            for (int dc = 0; dc < 4; ++dc) {
                const int o = (dc * 32 + h * 8) ^ sw;
                short8 kfh = *(const short8*)(krh + o);
                short8 kfl = *(const short8*)(krl + o);
                s = __builtin_amdgcn_mfma_f32_16x16x32_bf16(kfh, qfh[dc], s, 0, 0, 0);
                s = __builtin_amdgcn_mfma_f32_16x16x32_bf16(kfh, qfl[dc], s, 0, 0, 0);
                s = __builtin_amdgcn_mfma_f32_16x16x32_bf16(kfl, qfh[dc], s, 0, 0, 0);
            }
            if (tile0 + NK > T) {   // tail mask (zero-padded keys must become -inf)
#pragma unroll
                for (int r = 0; r < 4; ++r)
                    if (tile0 + c * 16 + h * 4 + r >= T) s[r] = -1e30f;
            }
#pragma unroll
            for (int r = 0; r < 4; ++r) sc[c * 4 + r] = s[r];
        }

        // ---- online softmax: lane holds 16 of the row's 64 scores; full row via xor 16/32 ----
        float mloc = sc[0];
#pragma unroll
        for (int i = 1; i < 16; ++i) mloc = fmaxf(mloc, sc[i]);
        mloc = fmaxf(mloc, __shfl_xor(mloc, 16));
        mloc = fmaxf(mloc, __shfl_xor(mloc, 32));
        const float mnew = fmaxf(m_run, mloc);
        float lloc = 0.f;
#pragma unroll
        for (int i = 0; i < 16; ++i) {
            float pv = __expf(sc[i] - mnew);
            sc[i] = pv;
            lloc += pv;
        }
        lloc += __shfl_xor(lloc, 16);
        lloc += __shfl_xor(lloc, 32);
        const float alpha = __expf(m_run - mnew);
        l_run = l_run * alpha + lloc;
        m_run = mnew;
#pragma unroll
        for (int db = 0; db < 8; ++db) acc[db] = acc[db] * alpha;

        // ---- PV: swapped (A=V^T, B=P). Slot t = 32g + 4h + (j&3) + 16*(j>>2)
        //      => P fragment is exactly sc[8g + j] (in registers), V^T frag = 2x ds_read_b64.
#pragma unroll
        for (int g = 0; g < 2; ++g) {
            short8 pf;
#pragma unroll
            for (int j = 0; j < 8; ++j) pf[j] = (short)bf16_rne(sc[g * 8 + j]);
#pragma unroll
            for (int db = 0; db < 8; ++db) {
                const int drow = db * 16 + m;
                const ushort* vr = &vts[drow * NK];
                const int sw = (drow & 15) << 2;
                short4v a0 = *(const short4v*)(vr + ((g * 32 + h * 4) ^ sw));
                short4v a1 = *(const short4v*)(vr + ((g * 32 + 16 + h * 4) ^ sw));
                short8 vf = __builtin_shufflevector(a0, a1, 0, 1, 2, 3, 4, 5, 6, 7);
                acc[db] = __builtin_amdgcn_mfma_f32_16x16x32_bf16(vf, pf, acc[db], 0, 0, 0);
            }
        }
    }

    // ---- epilogue: lane l, acc[db] reg r -> out[qrow][16db + 4h + r] ----
    const float inv_l = 1.f / l_run;
    float* dst = outg + (((long)(batch * NN + head)) * SS + qrow) * DD;
#pragma unroll
    for (int db = 0; db < 8; ++db) {
        float4 o = make_float4(acc[db][0] * inv_l, acc[db][1] * inv_l,
                               acc[db][2] * inv_l, acc[db][3] * inv_l);
        *(float4*)(dst + db * 16 + h * 4) = o;
    }
}

extern "C" void kernel_launch(void* const* d_in, const int* in_sizes, int n_in,
                              void* d_out, int out_size, void* d_ws, size_t ws_size,
                              hipStream_t stream) {
    const float* q      = (const float*)d_in[0];
    const float* k      = (const float*)d_in[1];
    const float* v      = (const float*)d_in[2];
    const float* mem_kv = (const float*)d_in[3];
    const int*   sp     = (const int*)d_in[4];
    float* out = (float*)d_out;

    dim3 grid(512);    // (SS/MQ) * NN * BB, XCD-grouped decode in-kernel
    dim3 block(512);
    hipLaunchKernelGGL(mra_attn_mfma, grid, block, 0, stream, q, k, v, mem_kv, sp, out);
}